// Round 1
// baseline (553.551 us; speedup 1.0000x reference)
//
#include <hip/hip_runtime.h>

#define THRESH 0.1f
#define LINE 64

// One 64-lane wave processes one 64-element cacheline.
// Iterative base extraction: the first still-uncovered lane (in index order)
// is the next base in creation order (matches the reference's append order);
// broadcast its value, snap every uncovered lane within THRESH to it.
// First-match-wins is preserved because bases are processed in creation order
// and a lane is only assignable while uncovered.
__global__ __launch_bounds__(256, 8) void cluster_kernel(
    const float* __restrict__ in, float* __restrict__ out,
    long long n_lines, long long total)
{
    const int lane = threadIdx.x & 63;
    const long long n_waves = ((long long)gridDim.x * blockDim.x) >> 6;
    long long line = ((long long)blockIdx.x * blockDim.x + threadIdx.x) >> 6;

    if (line < n_lines) {
        float x = in[line * LINE + lane];
        for (;;) {
            // Prefetch next line before the data-dependent clustering loop.
            const long long next = line + n_waves;
            float xn = 0.0f;
            if (next < n_lines) xn = in[next * LINE + lane];

            float o = x;
            bool covered = false;
            unsigned long long uncovered = ~0ULL;
            while (uncovered) {
                int b = __ffsll(uncovered) - 1;
                b = __builtin_amdgcn_readfirstlane(b);
                const float base =
                    __int_as_float(__builtin_amdgcn_readlane(__float_as_int(x), b));
                const bool m = (!covered) && (fabsf(x - base) < THRESH);
                if (m) { o = base; covered = true; }
                uncovered &= ~__ballot(m);
            }
            out[line * LINE + lane] = o;

            if (next >= n_lines) break;
            x = xn;
            line = next;
        }
    }

    // Tail elements past the last full cacheline are copied unchanged.
    // (For this problem size total % 64 == 0, so this loop is empty.)
    const long long tail_start = n_lines * LINE;
    for (long long i = tail_start + (long long)blockIdx.x * blockDim.x + threadIdx.x;
         i < total; i += (long long)gridDim.x * blockDim.x) {
        out[i] = in[i];
    }
}

extern "C" void kernel_launch(void* const* d_in, const int* in_sizes, int n_in,
                              void* d_out, int out_size, void* d_ws, size_t ws_size,
                              hipStream_t stream) {
    const float* x = (const float*)d_in[0];
    float* out = (float*)d_out;
    const long long total = (long long)in_sizes[0];
    const long long n_lines = total / LINE;

    // 2048 blocks x 256 threads = 8192 waves = full residency on 256 CUs
    // at 8 waves/SIMD; each wave grid-strides over ~98 lines.
    const int block = 256;
    const int grid = 2048;
    cluster_kernel<<<grid, block, 0, stream>>>(x, out, n_lines, total);
}

// Round 6
// 471.005 us; speedup vs baseline: 1.1753x; 1.1753x over previous
//
#include <hip/hip_runtime.h>

#define LINE 64

// Wave-parallel first-fit clustering of one 64-float cacheline per line,
// two lines interleaved per wave.
//
// Invariant (matches reference, absmax==0.0 verified in R1): bases are
// created in increasing index order; extracting the first still-uncovered
// lane (s_ff1) as the next base and snapping all uncovered lanes within
// THRESH to it reproduces "first earlier base within threshold" exactly.
//
// Inner loop is hand-scheduled asm: 5 VALU + 3 SALU per line-iteration.
//  - gfx950 gotcha: v_cndmask with an SGPR data operand + implicit vcc read
//    violates the constant-bus limit (R3 compile error) -> broadcast base
//    to a VGPR with v_mov first; cndmask is then all-VGPR + vcc.
//  - finished line (uncov==0) iterates as a harmless no-op (match mask = 0),
//    so the pair loops to max(nA,nB) with no divergence handling.
//  - v_readlane->SGPR-read hazard covered by interleave + s_nop 1.
//  - s_ff1 of 0 returns -1 -> readlane lane 63 -> harmless no-op iteration.
__device__ __forceinline__ void cluster_pair(float xA, float xB, float thr,
                                             float& oA_out, float& oB_out) {
  float oA = xA, oB = xB;
  float dA, dB, vbA, vbB;
  float sbA, sbB;            // SGPR broadcasts
  unsigned long long unA, unB;
  int bA, bB;
  asm volatile(
      "s_mov_b64 %[unA], -1\n\t"
      "s_mov_b64 %[unB], -1\n\t"
      "s_mov_b32 %[bA], 0\n\t"
      "s_mov_b32 %[bB], 0\n\t"
      "1:\n\t"
      "v_readlane_b32 %[sbA], %[xA], %[bA]\n\t"
      "v_readlane_b32 %[sbB], %[xB], %[bB]\n\t"
      "s_nop 1\n\t"
      "v_mov_b32 %[vbA], %[sbA]\n\t"
      "v_mov_b32 %[vbB], %[sbB]\n\t"
      "v_sub_f32 %[dA], %[vbA], %[xA]\n\t"
      "v_cmp_gt_f32 vcc, %[t], abs(%[dA])\n\t"
      "s_and_b64 vcc, vcc, %[unA]\n\t"           // vcc = match_A
      "v_cndmask_b32 %[oA], %[oA], %[vbA], vcc\n\t"
      "s_andn2_b64 %[unA], %[unA], vcc\n\t"      // uncovA &= ~match_A
      "s_ff1_i32_b64 %[bA], %[unA]\n\t"          // next base A (-1 if done)
      "v_sub_f32 %[dB], %[vbB], %[xB]\n\t"
      "v_cmp_gt_f32 vcc, %[t], abs(%[dB])\n\t"
      "s_and_b64 vcc, vcc, %[unB]\n\t"
      "v_cndmask_b32 %[oB], %[oB], %[vbB], vcc\n\t"
      "s_andn2_b64 %[unB], %[unB], vcc\n\t"
      "s_ff1_i32_b64 %[bB], %[unB]\n\t"
      "s_or_b64 vcc, %[unA], %[unB]\n\t"         // SCC = any uncovered
      "s_cbranch_scc1 1b\n\t"
      : [oA] "+v"(oA), [oB] "+v"(oB),
        [dA] "=&v"(dA), [dB] "=&v"(dB),
        [vbA] "=&v"(vbA), [vbB] "=&v"(vbB),
        [sbA] "=&s"(sbA), [sbB] "=&s"(sbB),
        [unA] "=&s"(unA), [unB] "=&s"(unB),
        [bA] "=&s"(bA), [bB] "=&s"(bB)
      : [xA] "v"(xA), [xB] "v"(xB), [t] "s"(thr)
      : "vcc", "scc");
  oA_out = oA;
  oB_out = oB;
}

__global__ __launch_bounds__(256, 8) void cluster_kernel(
    const float* __restrict__ in, float* __restrict__ out,
    long long n_lines, long long total)
{
  const int lane = threadIdx.x & 63;
  const long long wid = ((long long)blockIdx.x * blockDim.x + threadIdx.x) >> 6;
  const long long n_waves = ((long long)gridDim.x * blockDim.x) >> 6;
  const long long n_pairs = (n_lines + 1) >> 1;

  long long pair = wid;
  if (pair < n_pairs) {
    long long lA = 2 * pair, lB = 2 * pair + 1;
    float xA = in[lA * LINE + lane];
    float xB = (lB < n_lines) ? in[lB * LINE + lane] : xA;
    for (;;) {
      // Prefetch next pair before the data-dependent clustering loop.
      const long long np = pair + n_waves;
      const bool has_next = np < n_pairs;
      float xA2 = 0.f, xB2 = 0.f;
      if (has_next) {
        const long long nA = 2 * np, nB = 2 * np + 1;
        xA2 = in[nA * LINE + lane];
        xB2 = (nB < n_lines) ? in[nB * LINE + lane] : xA2;
      }

      float oA, oB;
      cluster_pair(xA, xB, 0.1f, oA, oB);

      out[2 * pair * LINE + lane] = oA;
      if (2 * pair + 1 < n_lines) out[(2 * pair + 1) * LINE + lane] = oB;

      if (!has_next) break;
      xA = xA2; xB = xB2; pair = np;
    }
  }

  // Elements past the last full cacheline are copied unchanged (empty here).
  const long long tail = n_lines * LINE;
  for (long long i = tail + (long long)blockIdx.x * blockDim.x + threadIdx.x;
       i < total; i += (long long)gridDim.x * blockDim.x)
    out[i] = in[i];
}

extern "C" void kernel_launch(void* const* d_in, const int* in_sizes, int n_in,
                              void* d_out, int out_size, void* d_ws, size_t ws_size,
                              hipStream_t stream) {
  const float* x = (const float*)d_in[0];
  float* out = (float*)d_out;
  const long long total = (long long)in_sizes[0];
  const long long n_lines = total / LINE;

  // 2048 blocks x 256 threads = 8192 waves = full residency (256 CU x 8/SIMD);
  // each wave grid-strides over ~49 line-pairs.
  const int block = 256;
  const int grid = 2048;
  cluster_kernel<<<grid, block, 0, stream>>>(x, out, n_lines, total);
}